// Round 4
// baseline (733.440 us; speedup 1.0000x reference)
//
#include <hip/hip_runtime.h>
#include <math.h>

#define DEPTH 17
#define NNODES ((1 << DEPTH) - 1)

typedef _Float16 f16x8 __attribute__((ext_vector_type(8)));
typedef float f32x4 __attribute__((ext_vector_type(4)));

__device__ __forceinline__ float sigmoid_(float v) {
  return 1.0f / (1.0f + __expf(-v));
}
__device__ __forceinline__ float tanh_(float v) {
  float t = __expf(-2.0f * fabsf(v));
  float r = (1.0f - t) / (1.0f + t);
  return v < 0.0f ? -r : r;
}

// Lane-order-packed weights: for each (nb, w, g, c, ks) a 16x32 f16 tile
// (cols l15 = 0..15, k = c*64+ks*32 .. +31) stored so that lane (q*16+l15)
// holds elems l15*32 + q*8 .. +7 -> one wave B-fragment load = contiguous
// 1 KB, perfectly coalesced, L2-resident (1.97 MB total).
// Logical col = g*256 + nb*64 + w*16 + l15; rows 0..767 = [W_iou|U_iou],
// rows 768..1279 = [0|U_f_w] (f-gates), K contiguous.
__global__ __launch_bounds__(256) void build_wb2(
    _Float16* __restrict__ Wb2, const float* __restrict__ W_iou,
    const float* __restrict__ U_iou, const float* __restrict__ U_f_w) {
  int idx = blockIdx.x * 256 + threadIdx.x;  // grid covers 1280*768 exactly
  int within = idx & 511;                    // l15*32 + kk
  int blk = idx >> 9;                        // ((nb*4+w)*5 + g)*24 + c*2+ks
  int l15 = within >> 5;
  int kk = within & 31;
  int cb = blk % 24;                         // c*2+ks
  int t = blk / 24;
  int g = t % 5;
  int t2 = t / 5;
  int w = t2 & 3;
  int nb = t2 >> 2;
  int col = g * 256 + nb * 64 + w * 16 + l15;
  int k = cb * 32 + kk;
  float v;
  if (col < 768)
    v = (k < 256) ? W_iou[col * 256 + k] : U_iou[col * 512 + (k - 256)];
  else
    v = (k < 256) ? 0.0f : U_f_w[(col - 768) * 512 + (k - 256)];
  Wb2[idx] = (_Float16)v;
}

// One level: fused GEMM (A[m, K] @ Wb^T) + TreeLSTM node apply.
// Block tile: 64 rows x 64 n (x NG gate groups); 4 waves, wave w owns all 64
// rows for n = nb*64 + w*16 + l15 across ALL groups -> wave-local epilogue.
// B comes straight from the lane-packed L2-resident Wb2 (no LDS, no staging).
// A double-buffered in LDS (16 KB), reg-staged 1.5 chunks ahead; ONE barrier
// per chunk. XOR swizzle kc^(row&7) keeps ds_read_b128 conflict-free.
template <bool LEAF, bool H16, int MINW, typename CT>
__global__ __launch_bounds__(256, MINW) void level_kernel(
    const float* __restrict__ x, const float* __restrict__ c0in,
    const _Float16* __restrict__ Wb2, const float* __restrict__ b_iou,
    const float* __restrict__ U_f_b, float* __restrict__ out,
    CT* __restrict__ cws, _Float16* __restrict__ hws, int m, int off,
    int coff) {
  constexpr int NG = LEAF ? 3 : 5;    // gate groups of 64 output cols
  constexpr int NCH = LEAF ? 4 : 12;  // K / 64
  __shared__ f16x8 sA[2][64 * 8];     // 2 x 8 KB, double-buffered

  const int tid = threadIdx.x;
  const int w = tid >> 6;
  const int lane = tid & 63;
  const int l15 = lane & 15;
  const int q = lane >> 4;
  const int pbase = blockIdx.x << 6;
  const int nb = blockIdx.y;  // n-split, 0..3

  const int arow = tid >> 3;  // staging row for unit 0 (unit j: +32)
  const int akc = tid & 7;    // 16B unit within 64-k row

  float4 ax[2][2];
  f16x8 ah[2];

  // ---- issue global loads for A chunk c into registers (no waits here)
  auto LOADA = [&](int c) {
    const int k0 = (c << 6) + (akc << 3);
#pragma unroll
    for (int j = 0; j < 2; ++j) {
      const int row = arow + j * 32;
      const int p = pbase + row;
      const bool xpart = LEAF || c < 4;
      if (p < m) {
        if (xpart) {
          const float* src = x + (size_t)(off + p) * 256 + k0;
          ax[j][0] = *(const float4*)src;
          ax[j][1] = *(const float4*)(src + 4);
        } else if (H16) {
          ah[j] = *(const f16x8*)(hws + (size_t)(coff + 2 * p) * 256 +
                                  (k0 - 256));
        } else {
          const float* src = out + (size_t)(coff + 2 * p) * 256 + (k0 - 256);
          ax[j][0] = *(const float4*)src;
          ax[j][1] = *(const float4*)(src + 4);
        }
      } else {
        ax[j][0] = float4{0.f, 0.f, 0.f, 0.f};
        ax[j][1] = float4{0.f, 0.f, 0.f, 0.f};
        f16x8 z = {};
        ah[j] = z;
      }
    }
  };

  // ---- convert + ds_write staged regs into swizzled slots of buf c&1
  auto WRITEA = [&](int c) {
#pragma unroll
    for (int j = 0; j < 2; ++j) {
      const int row = arow + j * 32;
      f16x8 v;
      if (H16 && !LEAF && c >= 4) {
        v = ah[j];
      } else {
        v[0] = (_Float16)ax[j][0].x; v[1] = (_Float16)ax[j][0].y;
        v[2] = (_Float16)ax[j][0].z; v[3] = (_Float16)ax[j][0].w;
        v[4] = (_Float16)ax[j][1].x; v[5] = (_Float16)ax[j][1].y;
        v[6] = (_Float16)ax[j][1].z; v[7] = (_Float16)ax[j][1].w;
      }
      sA[c & 1][(row << 3) | (akc ^ (row & 7))] = v;
    }
  };

  // per-wave packed B base; (g,c,ks) tile at + (g*24 + c*2 + ks)*512
  const _Float16* bb =
      Wb2 + (size_t)(nb * 4 + w) * (5 * 24 * 512) + l15 * 32 + q * 8;

  f32x4 acc[NG][4] = {};

  LOADA(0);
  WRITEA(0);
  if (NCH > 1) LOADA(1);
  __syncthreads();

  for (int c = 0; c < NCH; ++c) {
    __builtin_amdgcn_s_setprio(1);
#pragma unroll
    for (int ks = 0; ks < 2; ++ks) {
      f16x8 af[4];
#pragma unroll
      for (int rf = 0; rf < 4; ++rf) {
        const int row = rf * 16 + l15;
        af[rf] = sA[c & 1][(row << 3) | ((ks * 4 + q) ^ (row & 7))];
      }
#pragma unroll
      for (int g = 0; g < NG; ++g) {
        const f16x8 bf = *(const f16x8*)(bb + ((g * 24 + c * 2 + ks) << 9));
#pragma unroll
        for (int rf = 0; rf < 4; ++rf)
          acc[g][rf] = __builtin_amdgcn_mfma_f32_16x16x32_f16(
              af[rf], bf, acc[g][rf], 0, 0, 0);
      }
    }
    __builtin_amdgcn_s_setprio(0);
    if (c + 1 < NCH) {
      WRITEA(c + 1);                 // waits A(c+1) vmcnt here (post-compute)
      if (c + 2 < NCH) LOADA(c + 2); // 1.5 chunks ahead
    }
    __syncthreads();                 // one barrier per chunk
  }

  // ---- epilogue: gates in f32, write h (d_out [+f16 ws]) and c (ws)
  const int n = nb * 64 + w * 16 + l15;  // n in [0,256)
  const float bi = b_iou[n];
  const float bo = b_iou[256 + n];
  const float bu = b_iou[512 + n];
  float bf0 = 0.f, bf1 = 0.f;
  if (!LEAF) { bf0 = U_f_b[n]; bf1 = U_f_b[256 + n]; }
#pragma unroll
  for (int rf = 0; rf < 4; ++rf) {
#pragma unroll
    for (int r = 0; r < 4; ++r) {
      const int p = pbase + rf * 16 + (q << 2) + r;
      if (p < m) {
        const float iv = sigmoid_(acc[0][rf][r] + bi);
        const float ov = sigmoid_(acc[1][rf][r] + bo);
        const float uv = tanh_(acc[2][rf][r] + bu);
        float cred;
        if (LEAF) {
          cred = c0in[(size_t)(off + p) * 256 + n];
        } else {
          const size_t cb = (size_t)(coff + 2 * p) * 256 + n;
          const float f0 = sigmoid_(acc[3][rf][r] + bf0);
          const float f1 = sigmoid_(acc[4][rf][r] + bf1);
          cred = f0 * (float)cws[cb] + f1 * (float)cws[cb + 256];
        }
        const float cc = iv * uv + cred;
        const float hh = ov * tanh_(cc);
        const size_t ob = (size_t)(off + p) * 256 + n;
        out[ob] = hh;
        cws[ob] = (CT)cc;
        if (H16) hws[ob] = (_Float16)hh;
      }
    }
  }
}

template <bool H16, typename CT>
static void run_levels(const float* x, const float* c0, const _Float16* Wb2,
                       const float* b_iou, const float* U_f_b, float* out,
                       CT* cws, _Float16* hws, hipStream_t stream) {
  // leaves: level 16, m = 65536, off = 65535
  level_kernel<true, H16, 4, CT><<<dim3(1024, 4), 256, 0, stream>>>(
      x, c0, Wb2, b_iou, U_f_b, out, cws, hws, 65536, 65535, 0);
  for (int k = DEPTH - 2; k >= 0; --k) {
    const int m = 1 << k;
    level_kernel<false, H16, 3, CT>
        <<<dim3((m + 63) / 64, 4), 256, 0, stream>>>(
            x, c0, Wb2, b_iou, U_f_b, out, cws, hws, m, m - 1, 2 * m - 1);
  }
}

extern "C" void kernel_launch(void* const* d_in, const int* in_sizes, int n_in,
                              void* d_out, int out_size, void* d_ws, size_t ws_size,
                              hipStream_t stream) {
  const float* x     = (const float*)d_in[0];
  // d_in[1] = h0 (unused by the reference's math)
  const float* c0    = (const float*)d_in[2];
  const float* W_iou = (const float*)d_in[3];
  const float* U_iou = (const float*)d_in[4];
  const float* b_iou = (const float*)d_in[5];
  const float* U_f_w = (const float*)d_in[6];
  const float* U_f_b = (const float*)d_in[7];
  float* out = (float*)d_out;

  char* ws = (char*)d_ws;
  const size_t wbBytes = (size_t)1280 * 768 * 2;  // 1.97 MB, 16B-aligned
  _Float16* Wb2 = (_Float16*)ws;
  build_wb2<<<3840, 256, 0, stream>>>(Wb2, W_iou, U_iou, U_f_w);

  const size_t cElems = (size_t)NNODES * 256;
  char* p1 = ws + wbBytes;
  if (ws_size >= wbBytes + cElems * 4 + cElems * 2) {
    // c in f32, h mirrored in f16 (identical numerics to the MFMA staging)
    run_levels<true, float>(x, c0, Wb2, b_iou, U_f_b, out, (float*)p1,
                            (_Float16*)(p1 + cElems * 4), stream);
  } else if (ws_size >= wbBytes + cElems * 4) {
    run_levels<false, float>(x, c0, Wb2, b_iou, U_f_b, out, (float*)p1,
                             nullptr, stream);
  } else {
    run_levels<false, _Float16>(x, c0, Wb2, b_iou, U_f_b, out, (_Float16*)p1,
                                nullptr, stream);
  }
}

// Round 5
// 584.029 us; speedup vs baseline: 1.2558x; 1.2558x over previous
//
#include <hip/hip_runtime.h>
#include <math.h>

#define DEPTH 17
#define NNODES ((1 << DEPTH) - 1)

typedef _Float16 f16x8 __attribute__((ext_vector_type(8)));
typedef float f32x4 __attribute__((ext_vector_type(4)));

__device__ __forceinline__ float sigmoid_(float v) {
  return 1.0f / (1.0f + __expf(-v));
}
__device__ __forceinline__ float tanh_(float v) {
  float t = __expf(-2.0f * fabsf(v));
  float r = (1.0f - t) / (1.0f + t);
  return v < 0.0f ? -r : r;
}

// Lane-order-packed weights: for each (nb, w, g, cb) a 16x32 f16 tile
// (cols l15 = 0..15, k = cb*32 .. +31) stored so lane (q*16+l15) holds
// elems l15*32 + q*8 .. +7 -> one wave B-fragment = contiguous 1 KB,
// coalesced, L2-resident (1.97 MB total).
// Logical col = g*256 + nb*64 + w*16 + l15; cols 0..767 = [W_iou|U_iou],
// 768..1279 = [0|U_f_w] (f-gates), K contiguous.
__global__ __launch_bounds__(256) void build_wb2(
    _Float16* __restrict__ Wb2, const float* __restrict__ W_iou,
    const float* __restrict__ U_iou, const float* __restrict__ U_f_w) {
  int idx = blockIdx.x * 256 + threadIdx.x;  // grid covers 1280*768 exactly
  int within = idx & 511;                    // l15*32 + kk
  int blk = idx >> 9;                        // ((nb*4+w)*5 + g)*24 + cb
  int l15 = within >> 5;
  int kk = within & 31;
  int cb = blk % 24;
  int t = blk / 24;
  int g = t % 5;
  int t2 = t / 5;
  int w = t2 & 3;
  int nb = t2 >> 2;
  int col = g * 256 + nb * 64 + w * 16 + l15;
  int k = cb * 32 + kk;
  float v;
  if (col < 768)
    v = (k < 256) ? W_iou[col * 256 + k] : U_iou[col * 512 + (k - 256)];
  else
    v = (k < 256) ? 0.0f : U_f_w[(col - 768) * 512 + (k - 256)];
  Wb2[idx] = (_Float16)v;
}

// One level: fused GEMM (A[m, K] @ Wb^T) + TreeLSTM node apply.
// Block tile: 64 rows x 64 n (x NG gate groups); 4 waves, wave w owns all 64
// rows for n = nb*64 + w*16 + l15 -> wave-local epilogue.
// Software pipeline (per 2-chunk iteration): A reg-sets ping-pong with
// prefetch distance 2 chunks (covers HBM ~900cyc); B reg-sets ping-pong with
// distance 1 chunk (covers L2 ~200cyc). A double-buffered in LDS (16 KB),
// XOR swizzle kc^(row&7), one barrier per chunk. B never touches LDS.
template <bool LEAF, bool H16, typename CT>
__global__ __launch_bounds__(256, 2) void level_kernel(
    const float* __restrict__ x, const float* __restrict__ c0in,
    const _Float16* __restrict__ Wb2, const float* __restrict__ b_iou,
    const float* __restrict__ U_f_b, float* __restrict__ out,
    CT* __restrict__ cws, _Float16* __restrict__ hws, int m, int off,
    int coff) {
  constexpr int NG = LEAF ? 3 : 5;    // gate groups of 64 output cols
  constexpr int NCH = LEAF ? 4 : 12;  // K / 64 (even)
  constexpr int NBU = NG * 2;         // B f16x8 fragments per chunk
  __shared__ f16x8 sA[2][64 * 8];     // 2 x 8 KB

  const int tid = threadIdx.x;
  const int w = tid >> 6;
  const int lane = tid & 63;
  const int l15 = lane & 15;
  const int q = lane >> 4;

  // XCD-grouped mapping: all 4 nb-splits of a row-group share bid%8 (same
  // XCD L2) and sit in one 32-block dispatch window. Requires R%8==0.
  int bx = blockIdx.x, r, nb;
  if ((gridDim.x & 31) == 0) {
    nb = (bx >> 3) & 3;
    r = ((bx >> 5) << 3) + (bx & 7);
  } else {
    r = bx >> 2;
    nb = bx & 3;
  }
  const int pbase = r << 6;

  const int arow = tid >> 3;  // staging row for unit 0 (unit j: +32)
  const int akc = tid & 7;    // 16B unit within 64-k row

  // ---- issue global A loads for chunk c into a register set (no waits)
  auto LOADA = [&](float4 (&ax)[2][2], f16x8 (&ah)[2], int c) {
    const int k0 = (c << 6) + (akc << 3);
#pragma unroll
    for (int j = 0; j < 2; ++j) {
      const int row = arow + j * 32;
      const int p = pbase + row;
      const bool xpart = LEAF || c < 4;
      if (p < m) {
        if (xpart) {
          const float* src = x + (size_t)(off + p) * 256 + k0;
          ax[j][0] = *(const float4*)src;
          ax[j][1] = *(const float4*)(src + 4);
        } else if (H16) {
          ah[j] = *(const f16x8*)(hws + (size_t)(coff + 2 * p) * 256 +
                                  (k0 - 256));
        } else {
          const float* src = out + (size_t)(coff + 2 * p) * 256 + (k0 - 256);
          ax[j][0] = *(const float4*)src;
          ax[j][1] = *(const float4*)(src + 4);
        }
      } else {
        ax[j][0] = float4{0.f, 0.f, 0.f, 0.f};
        ax[j][1] = float4{0.f, 0.f, 0.f, 0.f};
        f16x8 z = {};
        ah[j] = z;
      }
    }
  };

  // ---- convert + ds_write a staged set into swizzled slots of buf c&1
  auto WRITEA = [&](float4 (&ax)[2][2], f16x8 (&ah)[2], int c) {
#pragma unroll
    for (int j = 0; j < 2; ++j) {
      const int row = arow + j * 32;
      f16x8 v;
      if (H16 && !LEAF && c >= 4) {
        v = ah[j];
      } else {
        v[0] = (_Float16)ax[j][0].x; v[1] = (_Float16)ax[j][0].y;
        v[2] = (_Float16)ax[j][0].z; v[3] = (_Float16)ax[j][0].w;
        v[4] = (_Float16)ax[j][1].x; v[5] = (_Float16)ax[j][1].y;
        v[6] = (_Float16)ax[j][1].z; v[7] = (_Float16)ax[j][1].w;
      }
      sA[c & 1][(row << 3) | (akc ^ (row & 7))] = v;
    }
  };

  // per-wave packed B base; (g, cb=c*2+ks) tile at + (g*24 + cb)*512
  const _Float16* bb =
      Wb2 + (size_t)(nb * 4 + w) * (5 * 24 * 512) + l15 * 32 + q * 8;
  auto LOADB = [&](f16x8 (&bv)[NBU], int c) {
#pragma unroll
    for (int j = 0; j < NBU; ++j)
      bv[j] = *(const f16x8*)(bb + (((j >> 1) * 24 + c * 2 + (j & 1)) << 9));
  };

  f32x4 acc[NG][4] = {};

  auto COMPUTE = [&](int buf, f16x8 (&bv)[NBU]) {
    __builtin_amdgcn_s_setprio(1);
#pragma unroll
    for (int ks = 0; ks < 2; ++ks) {
      f16x8 af[4];
#pragma unroll
      for (int rf = 0; rf < 4; ++rf) {
        const int row = rf * 16 + l15;
        af[rf] = sA[buf][(row << 3) | ((ks * 4 + q) ^ (row & 7))];
      }
#pragma unroll
      for (int g = 0; g < NG; ++g) {
        const f16x8 bf = bv[g * 2 + ks];
#pragma unroll
        for (int rf = 0; rf < 4; ++rf)
          acc[g][rf] = __builtin_amdgcn_mfma_f32_16x16x32_f16(
              af[rf], bf, acc[g][rf], 0, 0, 0);
      }
    }
    __builtin_amdgcn_s_setprio(0);
  };

  float4 axA[2][2], axB[2][2];
  f16x8 ahA[2], ahB[2];
  f16x8 bvA[NBU], bvB[NBU];

  LOADA(axA, ahA, 0);
  LOADB(bvA, 0);
  WRITEA(axA, ahA, 0);
  LOADA(axB, ahB, 1);
  LOADB(bvB, 1);
  __syncthreads();

  for (int c = 0; c < NCH; c += 2) {
    if (c + 2 < NCH) LOADA(axA, ahA, c + 2);  // distance 2: use at WRITEA below
    COMPUTE(0, bvA);                          // chunk c
    WRITEA(axB, ahB, c + 1);
    if (c + 2 < NCH) LOADB(bvA, c + 2);       // distance 1 (L2)
    __syncthreads();
    if (c + 3 < NCH) LOADA(axB, ahB, c + 3);
    COMPUTE(1, bvB);                          // chunk c+1
    if (c + 2 < NCH) {
      WRITEA(axA, ahA, c + 2);
      if (c + 3 < NCH) LOADB(bvB, c + 3);
      __syncthreads();
    }
  }

  // ---- epilogue: gates in f32, write h (d_out [+f16 ws]) and c (ws)
  const int n = nb * 64 + w * 16 + l15;  // n in [0,256)
  const float bi = b_iou[n];
  const float bo = b_iou[256 + n];
  const float bu = b_iou[512 + n];
  float bf0 = 0.f, bf1 = 0.f;
  if (!LEAF) { bf0 = U_f_b[n]; bf1 = U_f_b[256 + n]; }
#pragma unroll
  for (int rf = 0; rf < 4; ++rf) {
#pragma unroll
    for (int rr = 0; rr < 4; ++rr) {
      const int p = pbase + rf * 16 + (q << 2) + rr;
      if (p < m) {
        const float iv = sigmoid_(acc[0][rf][rr] + bi);
        const float ov = sigmoid_(acc[1][rf][rr] + bo);
        const float uv = tanh_(acc[2][rf][rr] + bu);
        float cred;
        if (LEAF) {
          cred = c0in[(size_t)(off + p) * 256 + n];
        } else {
          const size_t cb = (size_t)(coff + 2 * p) * 256 + n;
          const float f0 = sigmoid_(acc[3][rf][rr] + bf0);
          const float f1 = sigmoid_(acc[4][rf][rr] + bf1);
          cred = f0 * (float)cws[cb] + f1 * (float)cws[cb + 256];
        }
        const float cc = iv * uv + cred;
        const float hh = ov * tanh_(cc);
        const size_t ob = (size_t)(off + p) * 256 + n;
        out[ob] = hh;
        cws[ob] = (CT)cc;
        if (H16) hws[ob] = (_Float16)hh;
      }
    }
  }
}

template <bool H16, typename CT>
static void run_levels(const float* x, const float* c0, const _Float16* Wb2,
                       const float* b_iou, const float* U_f_b, float* out,
                       CT* cws, _Float16* hws, hipStream_t stream) {
  // leaves: level 16, m = 65536, off = 65535
  level_kernel<true, H16, CT><<<dim3(4096), 256, 0, stream>>>(
      x, c0, Wb2, b_iou, U_f_b, out, cws, hws, 65536, 65535, 0);
  for (int k = DEPTH - 2; k >= 0; --k) {
    const int m = 1 << k;
    const int R = (m + 63) / 64;
    level_kernel<false, H16, CT><<<dim3(R * 4), 256, 0, stream>>>(
        x, c0, Wb2, b_iou, U_f_b, out, cws, hws, m, m - 1, 2 * m - 1);
  }
}

extern "C" void kernel_launch(void* const* d_in, const int* in_sizes, int n_in,
                              void* d_out, int out_size, void* d_ws, size_t ws_size,
                              hipStream_t stream) {
  const float* x     = (const float*)d_in[0];
  // d_in[1] = h0 (unused by the reference's math)
  const float* c0    = (const float*)d_in[2];
  const float* W_iou = (const float*)d_in[3];
  const float* U_iou = (const float*)d_in[4];
  const float* b_iou = (const float*)d_in[5];
  const float* U_f_w = (const float*)d_in[6];
  const float* U_f_b = (const float*)d_in[7];
  float* out = (float*)d_out;

  char* ws = (char*)d_ws;
  const size_t wbBytes = (size_t)1280 * 768 * 2;  // 1.97 MB, 16B-aligned
  _Float16* Wb2 = (_Float16*)ws;
  build_wb2<<<3840, 256, 0, stream>>>(Wb2, W_iou, U_iou, U_f_w);

  const size_t cElems = (size_t)NNODES * 256;
  char* p1 = ws + wbBytes;
  if (ws_size >= wbBytes + cElems * 2 + cElems * 2) {
    // c in f16 (halved traffic) + h mirrored in f16 for the parent GEMM
    run_levels<true, _Float16>(x, c0, Wb2, b_iou, U_f_b, out, (_Float16*)p1,
                               (_Float16*)(p1 + cElems * 2), stream);
  } else if (ws_size >= wbBytes + cElems * 4) {
    run_levels<false, float>(x, c0, Wb2, b_iou, U_f_b, out, (float*)p1,
                             nullptr, stream);
  } else {
    run_levels<false, _Float16>(x, c0, Wb2, b_iou, U_f_b, out, (_Float16*)p1,
                                nullptr, stream);
  }
}